// Round 19
// baseline (250.826 us; speedup 1.0000x reference)
//
#include <hip/hip_runtime.h>
#include <hip/hip_bf16.h>

typedef __attribute__((ext_vector_type(8))) short bf16x8;
typedef __attribute__((ext_vector_type(4))) float f32x4;
typedef __attribute__((ext_vector_type(4))) unsigned int u32x4;
typedef _Float16 half2_ __attribute__((ext_vector_type(2)));

__device__ __forceinline__ unsigned short f2bf(float f) {
    unsigned int x = __float_as_uint(f);
    x += 0x7fffu + ((x >> 16) & 1u);
    return (unsigned short)(x >> 16);
}

__device__ __forceinline__ float sigmoidf_(float x) {
    return 1.f / (1.f + __expf(-x));
}
__device__ __forceinline__ float tanhf_(float x) {
    float e = __expf(-2.f * fabsf(x));
    float t = (1.f - e) / (1.f + e);
    return copysignf(t, x);
}

__device__ __forceinline__ float fdot2_(unsigned int w, unsigned int h, float acc) {
#if __has_builtin(__builtin_amdgcn_fdot2)
    return __builtin_amdgcn_fdot2(__builtin_bit_cast(half2_, w),
                                  __builtin_bit_cast(half2_, h), acc, false);
#else
    half2_ a = __builtin_bit_cast(half2_, w);
    half2_ b = __builtin_bit_cast(half2_, h);
    return acc + (float)a.x * (float)b.x + (float)a.y * (float)b.y;
#endif
}

// ---------------------------------------------------------------------------
// One-hot builder (standalone small launch; unblocks the merged prep+seg).
// ---------------------------------------------------------------------------
__global__ __launch_bounds__(256) void onehot_build(
    const int* __restrict__ mask, short* __restrict__ onehot) {
    int b = blockIdx.x;
    int tid = threadIdx.x;
    short* oh = onehot + (size_t)b * 64 * 512;
    for (int i = tid; i < 64 * 512 / 8; i += 256) {
        bf16x8 z = {};
        *(bf16x8*)(oh + i * 8) = z;
    }
    __syncthreads();
    for (int t = tid; t < 512; t += 256) {
        unsigned int m = (unsigned int)mask[b * 512 + t];
        if (m < 50u) oh[(size_t)m * 512 + t] = (short)0x3F80;  // bf16 1.0
    }
}

// ---------------------------------------------------------------------------
// Prep bodies.
// ---------------------------------------------------------------------------
__device__ void convT_body(const float* __restrict__ srcF,
                           const float* __restrict__ srcB,
                           short* __restrict__ dst, int Ksrc, int Kpad,
                           int Nhalf, int bx, int by, float* tile /*64x65*/) {
    int k0 = bx * 64, n0 = by * 64;
    const float* src = (n0 < Nhalf) ? srcF : srcB;
    int ncol0 = (n0 < Nhalf) ? n0 : n0 - Nhalf;
    int c = threadIdx.x & 63;
    int r4 = threadIdx.x >> 6;
    for (int rr = r4; rr < 64; rr += 4) {
        int k = k0 + rr;
        tile[rr * 65 + c] = (k < Ksrc) ? src[(size_t)k * Nhalf + ncol0 + c] : 0.f;
    }
    __syncthreads();
    int rn = threadIdx.x >> 2, q = threadIdx.x & 3;
    short* d = dst + (size_t)(n0 + rn) * Kpad + k0 + q * 16;
    #pragma unroll
    for (int i = 0; i < 16; i++) d[i] = (short)f2bf(tile[(q * 16 + i) * 65 + rn]);
}

__device__ void conv_rec_pack_body(const float* __restrict__ WrF,
                                   const float* __restrict__ WrB,
                                   unsigned int* __restrict__ dst, int K, int N,
                                   int kq, int dir) {
    const float* src = dir ? WrB : WrF;
    int kqq = kq >> 2, q = kq & 3;
    for (int c = threadIdx.x; c < N; c += 256) {
        half2_ h;
        h.x = (_Float16)src[(size_t)(2 * kq) * N + c];
        h.y = (_Float16)src[(size_t)(2 * kq + 1) * N + c];
        dst[(((size_t)dir * (K / 8) + kqq) * N + c) * 4 + q] =
            __builtin_bit_cast(unsigned int, h);
    }
}

__device__ void concat_body(const float* __restrict__ lstm_in,
                            short* __restrict__ concatB, int b) {
    int tid = threadIdx.x;
    for (int idx = tid; idx < 50 * 64; idx += 256) {
        int m = idx >> 6, q = idx & 63;
        float v = (q < 8) ? lstm_in[(b * 50 + m) * 8 + q] : 0.f;
        concatB[(size_t)(b * 50 + m) * 832 + 768 + q] = (short)f2bf(v);
    }
}

// ---------------------------------------------------------------------------
// Segment-reduce GEMM body: merged[b] = onehot[b] @ hidden[b] / 50.
// ---------------------------------------------------------------------------
__device__ void seg_gemm_body(const float* __restrict__ hidden,
                              const short* __restrict__ onehot,
                              short* __restrict__ concatB, int b, int ny,
                              short (*Al)[36], short (*Bl)[36]) {
    int n0 = ny * 64;
    int tid = threadIdx.x;
    int lane = tid & 63, w = tid >> 6;
    int fr = lane & 15, fq = lane >> 4;
    int wc = w * 16;
    int arow = tid >> 2, apart = tid & 3;
    int nloc = tid & 63, kq = tid >> 6;

    f32x4 acc[4] = {};

    const short* ohb = onehot + (size_t)b * 64 * 512;
    const float* hbase = hidden + (size_t)b * 512 * 768 + n0 + nloc;

    bf16x8 aReg = *(const bf16x8*)(ohb + (size_t)arow * 512 + apart * 8);
    float bReg[8];
    #pragma unroll
    for (int kk = 0; kk < 8; kk++)
        bReg[kk] = hbase[(size_t)(kq * 8 + kk) * 768];

    for (int k0 = 0; k0 < 512; k0 += 32) {
        *(bf16x8*)&Al[arow][apart * 8] = aReg;
        #pragma unroll
        for (int kk = 0; kk < 8; kk += 2) {
            unsigned int pk = (unsigned int)f2bf(bReg[kk]) |
                              ((unsigned int)f2bf(bReg[kk + 1]) << 16);
            *(unsigned int*)&Bl[nloc][kq * 8 + kk] = pk;
        }
        __syncthreads();
        if (k0 + 32 < 512) {
            int kn = k0 + 32;
            aReg = *(const bf16x8*)(ohb + (size_t)arow * 512 + kn + apart * 8);
            #pragma unroll
            for (int kk = 0; kk < 8; kk++)
                bReg[kk] = hbase[(size_t)(kn + kq * 8 + kk) * 768];
        }
        bf16x8 af[4], bfv;
        #pragma unroll
        for (int mi = 0; mi < 4; mi++)
            af[mi] = *(const bf16x8*)&Al[mi * 16 + fr][fq * 8];
        bfv = *(const bf16x8*)&Bl[wc + fr][fq * 8];
        #pragma unroll
        for (int mi = 0; mi < 4; mi++)
            acc[mi] = __builtin_amdgcn_mfma_f32_16x16x32_bf16(af[mi], bfv,
                                                              acc[mi], 0, 0, 0);
        __syncthreads();
    }
    const float inv = 1.f / 50.f;
    #pragma unroll
    for (int mi = 0; mi < 4; mi++) {
        #pragma unroll
        for (int r = 0; r < 4; r++) {
            int m = mi * 16 + fq * 4 + r;
            if (m < 50) {
                int col = n0 + wc + fr;
                concatB[(size_t)(b * 50 + m) * 832 + col] =
                    (short)f2bf(acc[mi][r] * inv);
            }
        }
    }
}

// ---------------------------------------------------------------------------
// Merged prep + seg_gemm: blocks 0..927 = prep (convT x544, pack x384,
// concat x64 blocks... ranges below); 928..1695 = seg_gemm (768 blocks).
// All outputs disjoint; seg depends only on onehot (built beforehand).
// ---------------------------------------------------------------------------
__global__ __launch_bounds__(256) void prep_seg(
    const float* __restrict__ l1f_k, const float* __restrict__ l1b_k,
    short* __restrict__ wk1T,
    const float* __restrict__ l2f_k, const float* __restrict__ l2b_k,
    short* __restrict__ wk2T,
    const float* __restrict__ l1f_r, const float* __restrict__ l1b_r,
    unsigned int* __restrict__ wp1,
    const float* __restrict__ l2f_r, const float* __restrict__ l2b_r,
    unsigned int* __restrict__ wp2,
    const float* __restrict__ lstm_in,
    const float* __restrict__ hidden, const short* __restrict__ onehot,
    short* __restrict__ concatB) {
    __shared__ float tile[64 * 65];
    __shared__ short Al[64][36];
    __shared__ short Bl[64][36];
    int blk = blockIdx.x;
    if (blk < 416) {
        convT_body(l1f_k, l1b_k, wk1T, 776, 832, 1024, blk % 13, blk / 13, tile);
    } else if (blk < 544) {
        int q = blk - 416;
        convT_body(l2f_k, l2b_k, wk2T, 512, 512, 512, q % 8, q / 8, tile);
    } else if (blk < 800) {
        int q = blk - 544;
        conv_rec_pack_body(l1f_r, l1b_r, wp1, 256, 1024, q & 127, q >> 7);
    } else if (blk < 928) {
        int q = blk - 800;
        conv_rec_pack_body(l2f_r, l2b_r, wp2, 128, 512, q & 63, q >> 6);
    } else if (blk < 992) {
        concat_body(lstm_in, concatB, blk - 928);
    } else {
        int q = blk - 992;  // 768 seg blocks
        seg_gemm_body(hidden, onehot, concatB, q / 12, q % 12, Al, Bl);
    }
}

// ---------------------------------------------------------------------------
// bf16 MFMA GEMM, BK=64 + register prefetch (R16).
// ---------------------------------------------------------------------------
__global__ __launch_bounds__(256) void gemm_bf16(
    const short* __restrict__ A, const short* __restrict__ BT,
    const float* __restrict__ biasF, const float* __restrict__ biasB, int Nhalf,
    float* __restrict__ C, int M, int N, int Kpad) {
    __shared__ short Al[128][72];
    __shared__ short Bl[128][72];
    int m0 = blockIdx.x * 128, n0 = blockIdx.y * 128;
    int tid = threadIdx.x;
    int lane = tid & 63, w = tid >> 6;
    int srow = tid >> 1, shalf = tid & 1;
    int wr = (w >> 1) * 64, wc = (w & 1) * 64;
    int fr = lane & 15, fq = lane >> 4;

    f32x4 acc[4][4] = {};

    const short* aPtr = A + (size_t)(m0 + srow) * Kpad + shalf * 32;
    const short* bPtr = BT + (size_t)(n0 + srow) * Kpad + shalf * 32;
    bf16x8 av0 = *(const bf16x8*)(aPtr);
    bf16x8 av1 = *(const bf16x8*)(aPtr + 16);
    bf16x8 bv0 = *(const bf16x8*)(bPtr);
    bf16x8 bv1 = *(const bf16x8*)(bPtr + 16);

    for (int k0 = 0; k0 < Kpad; k0 += 64) {
        *(bf16x8*)&Al[srow][shalf * 32] = av0;
        *(bf16x8*)&Al[srow][shalf * 32 + 16] = av1;
        *(bf16x8*)&Bl[srow][shalf * 32] = bv0;
        *(bf16x8*)&Bl[srow][shalf * 32 + 16] = bv1;
        __syncthreads();
        if (k0 + 64 < Kpad) {
            av0 = *(const bf16x8*)(aPtr + k0 + 64);
            av1 = *(const bf16x8*)(aPtr + k0 + 80);
            bv0 = *(const bf16x8*)(bPtr + k0 + 64);
            bv1 = *(const bf16x8*)(bPtr + k0 + 80);
        }
        #pragma unroll
        for (int ks = 0; ks < 2; ks++) {
            bf16x8 af[4], bfv[4];
            #pragma unroll
            for (int mi = 0; mi < 4; mi++)
                af[mi] = *(const bf16x8*)&Al[wr + mi * 16 + fr][ks * 32 + fq * 8];
            #pragma unroll
            for (int ni = 0; ni < 4; ni++)
                bfv[ni] = *(const bf16x8*)&Bl[wc + ni * 16 + fr][ks * 32 + fq * 8];
            #pragma unroll
            for (int mi = 0; mi < 4; mi++)
                #pragma unroll
                for (int ni = 0; ni < 4; ni++)
                    acc[mi][ni] = __builtin_amdgcn_mfma_f32_16x16x32_bf16(
                        af[mi], bfv[ni], acc[mi][ni], 0, 0, 0);
        }
        __syncthreads();
    }
    #pragma unroll
    for (int mi = 0; mi < 4; mi++)
        #pragma unroll
        for (int ni = 0; ni < 4; ni++) {
            #pragma unroll
            for (int r = 0; r < 4; r++) {
                int row = m0 + wr + mi * 16 + fq * 4 + r;
                int col = n0 + wc + ni * 16 + fr;
                float bias = (col < Nhalf) ? biasF[col] : biasB[col - Nhalf];
                C[(size_t)row * N + col] = acc[mi][ni][r] + bias;
            }
        }
}

// ---------------------------------------------------------------------------
// LSTM layer-1 recurrence (R15: 104 us). 512 threads, 2 cols each; 25
// k-groups pinned in regs/AGPRs, 7 in LDS (112 KB); 2 waves/SIMD.
// ---------------------------------------------------------------------------
#define R1_REG 25
#define R1_LDS 7

__global__ __attribute__((amdgpu_flat_work_group_size(512, 512)))
__attribute__((amdgpu_waves_per_eu(2, 2))) void lstm_rec1(
    const float* __restrict__ xz, const unsigned int* __restrict__ wp,
    short* __restrict__ out1) {
    int b = blockIdx.x >> 1, dir = blockIdx.x & 1;
    const unsigned int* wd = wp + (size_t)dir * 32 * 1024 * 4;
    extern __shared__ char smem[];
    unsigned int* Wl = (unsigned int*)smem;                            // 112 KB
    unsigned int* h2u = (unsigned int*)(smem + R1_LDS * 1024 * 16);    // 128 u32
    float* zbuf = (float*)(smem + R1_LDS * 1024 * 16 + 512);           // 1024 f32
    int tid = threadIdx.x;
    int lane = tid & 63;
    int cA = tid, cB = tid + 512;

    unsigned int wA[R1_REG * 4], wB[R1_REG * 4];
    #pragma unroll
    for (int g = 0; g < R1_REG; g++) {
        u32x4 ta = *(const u32x4*)&wd[((size_t)g * 1024 + cA) * 4];
        u32x4 tb = *(const u32x4*)&wd[((size_t)g * 1024 + cB) * 4];
        wA[g * 4 + 0] = ta.x; wA[g * 4 + 1] = ta.y;
        wA[g * 4 + 2] = ta.z; wA[g * 4 + 3] = ta.w;
        wB[g * 4 + 0] = tb.x; wB[g * 4 + 1] = tb.y;
        wB[g * 4 + 2] = tb.z; wB[g * 4 + 3] = tb.w;
    }
    // One-time pin: asm outputs are not rematerializable.
    #pragma unroll
    for (int g = 0; g < R1_REG; g++) {
        asm volatile("" : "+v"(wA[g * 4 + 0]), "+v"(wA[g * 4 + 1]),
                          "+v"(wA[g * 4 + 2]), "+v"(wA[g * 4 + 3]),
                          "+v"(wB[g * 4 + 0]), "+v"(wB[g * 4 + 1]),
                          "+v"(wB[g * 4 + 2]), "+v"(wB[g * 4 + 3]));
    }
    #pragma unroll
    for (int g = 0; g < R1_LDS; g++) {
        *(u32x4*)&Wl[(g * 1024 + cA) * 4] =
            *(const u32x4*)&wd[((size_t)(R1_REG + g) * 1024 + cA) * 4];
        *(u32x4*)&Wl[(g * 1024 + cB) * 4] =
            *(const u32x4*)&wd[((size_t)(R1_REG + g) * 1024 + cB) * 4];
    }
    if (tid < 128) h2u[tid] = 0u;
    float cstate = 0.f;
    __syncthreads();

    for (int s = 0; s < 50; s++) {
        int tt = dir ? 49 - s : s;
        const float* xrow = xz + (size_t)(b * 50 + tt) * 2048 + dir * 1024;
        float xA = xrow[cA];
        float xB = xrow[cB];
        float zA0 = 0.f, zA1 = 0.f, zA2 = 0.f, zA3 = 0.f;
        float zB0 = 0.f, zB1 = 0.f, zB2 = 0.f, zB3 = 0.f;
        unsigned int hv0 = h2u[lane];
        unsigned int hv1 = h2u[lane + 64];
        #pragma unroll
        for (int g = 0; g < R1_REG; g++) {
            unsigned int src = (g < 16) ? hv0 : hv1;
            int base = (g < 16) ? 4 * g : 4 * (g - 16);
            unsigned int h0 = __builtin_amdgcn_readlane(src, base + 0);
            unsigned int h1 = __builtin_amdgcn_readlane(src, base + 1);
            unsigned int h2 = __builtin_amdgcn_readlane(src, base + 2);
            unsigned int h3 = __builtin_amdgcn_readlane(src, base + 3);
            zA0 = fdot2_(wA[g * 4 + 0], h0, zA0);
            zA1 = fdot2_(wA[g * 4 + 1], h1, zA1);
            zA2 = fdot2_(wA[g * 4 + 2], h2, zA2);
            zA3 = fdot2_(wA[g * 4 + 3], h3, zA3);
            zB0 = fdot2_(wB[g * 4 + 0], h0, zB0);
            zB1 = fdot2_(wB[g * 4 + 1], h1, zB1);
            zB2 = fdot2_(wB[g * 4 + 2], h2, zB2);
            zB3 = fdot2_(wB[g * 4 + 3], h3, zB3);
        }
        #pragma unroll
        for (int g = 0; g < R1_LDS; g++) {
            int gg = R1_REG + g;  // 25..31, all >= 16 -> hv1
            int base = 4 * (gg - 16);
            unsigned int h0 = __builtin_amdgcn_readlane(hv1, base + 0);
            unsigned int h1 = __builtin_amdgcn_readlane(hv1, base + 1);
            unsigned int h2 = __builtin_amdgcn_readlane(hv1, base + 2);
            unsigned int h3 = __builtin_amdgcn_readlane(hv1, base + 3);
            u32x4 wa = *(const u32x4*)&Wl[(g * 1024 + cA) * 4];
            u32x4 wb = *(const u32x4*)&Wl[(g * 1024 + cB) * 4];
            zA0 = fdot2_(wa.x, h0, zA0);
            zA1 = fdot2_(wa.y, h1, zA1);
            zA2 = fdot2_(wa.z, h2, zA2);
            zA3 = fdot2_(wa.w, h3, zA3);
            zB0 = fdot2_(wb.x, h0, zB0);
            zB1 = fdot2_(wb.y, h1, zB1);
            zB2 = fdot2_(wb.z, h2, zB2);
            zB3 = fdot2_(wb.w, h3, zB3);
        }
        zbuf[cA] = (zA0 + zA1) + (zA2 + zA3) + xA;
        zbuf[cB] = (zB0 + zB1) + (zB2 + zB3) + xB;
        __syncthreads();
        if (tid < 256) {
            float iv = sigmoidf_(zbuf[tid]);
            float fv = sigmoidf_(zbuf[tid + 256]);
            float gv = tanhf_(zbuf[tid + 512]);
            float ov = sigmoidf_(zbuf[tid + 768]);
            cstate = fv * cstate + iv * gv;
            float h = ov * tanhf_(cstate);
            ((_Float16*)h2u)[tid] = (_Float16)h;
            out1[(size_t)(b * 50 + tt) * 512 + dir * 256 + tid] = (short)f2bf(h);
        }
        __syncthreads();
    }
}

// ---------------------------------------------------------------------------
// LSTM layer-2 recurrence (R10 version). 512 threads, 1 col each; 16
// k-groups pinned once; h via readlane.
// ---------------------------------------------------------------------------
__global__ __launch_bounds__(512, 2) void lstm_rec2(
    const float* __restrict__ xz, const unsigned int* __restrict__ wp,
    float* __restrict__ out2) {
    int b = blockIdx.x >> 1, dir = blockIdx.x & 1;
    const unsigned int* wd = wp + (size_t)dir * 16 * 512 * 4;
    __shared__ unsigned int h2u[64];
    __shared__ float zbuf[512];
    int tid = threadIdx.x;
    int lane = tid & 63;
    unsigned int w[64];
    #pragma unroll
    for (int g = 0; g < 16; g++) {
        u32x4 t = *(const u32x4*)&wd[((size_t)g * 512 + tid) * 4];
        w[g * 4 + 0] = t.x; w[g * 4 + 1] = t.y;
        w[g * 4 + 2] = t.z; w[g * 4 + 3] = t.w;
    }
    #pragma unroll
    for (int g = 0; g < 16; g++) {
        asm volatile("" : "+v"(w[g * 4 + 0]), "+v"(w[g * 4 + 1]),
                          "+v"(w[g * 4 + 2]), "+v"(w[g * 4 + 3]));
    }
    if (tid < 64) h2u[tid] = 0u;
    float cstate = 0.f;
    __syncthreads();

    for (int s = 0; s < 50; s++) {
        int tt = dir ? 49 - s : s;
        float xv = xz[(size_t)(b * 50 + tt) * 1024 + dir * 512 + tid];
        float z0 = 0.f, z1 = 0.f, z2 = 0.f, z3 = 0.f;
        unsigned int hv = h2u[lane];
        #pragma unroll
        for (int g = 0; g < 16; g++) {
            unsigned int h0 = __builtin_amdgcn_readlane(hv, 4 * g + 0);
            unsigned int h1 = __builtin_amdgcn_readlane(hv, 4 * g + 1);
            unsigned int h2 = __builtin_amdgcn_readlane(hv, 4 * g + 2);
            unsigned int h3 = __builtin_amdgcn_readlane(hv, 4 * g + 3);
            z0 = fdot2_(w[g * 4 + 0], h0, z0);
            z1 = fdot2_(w[g * 4 + 1], h1, z1);
            z2 = fdot2_(w[g * 4 + 2], h2, z2);
            z3 = fdot2_(w[g * 4 + 3], h3, z3);
        }
        zbuf[tid] = (z0 + z1) + (z2 + z3) + xv;
        __syncthreads();
        if (tid < 128) {
            float iv = sigmoidf_(zbuf[tid]);
            float fv = sigmoidf_(zbuf[tid + 128]);
            float gv = tanhf_(zbuf[tid + 256]);
            float ov = sigmoidf_(zbuf[tid + 384]);
            cstate = fv * cstate + iv * gv;
            float h = ov * tanhf_(cstate);
            ((_Float16*)h2u)[tid] = (_Float16)h;
            if (s == 49) out2[b * 256 + dir * 128 + tid] = h;
        }
        __syncthreads();
    }
}

// ---------------------------------------------------------------------------
// Dense head: 256->128->64->32->1 with relu/sigmoid. One block per batch.
// ---------------------------------------------------------------------------
__global__ __launch_bounds__(128) void dense_head(
    const float* __restrict__ out2,
    const float* __restrict__ d1w, const float* __restrict__ d1b,
    const float* __restrict__ d3w, const float* __restrict__ d3b,
    const float* __restrict__ d5w, const float* __restrict__ d5b,
    const float* __restrict__ d7w, const float* __restrict__ d7b,
    float* __restrict__ out) {
    int b = blockIdx.x;
    int tid = threadIdx.x;
    __shared__ float x[256], y1[128], y2[64], y3[32];
    x[tid] = out2[b * 256 + tid];
    x[tid + 128] = out2[b * 256 + tid + 128];
    __syncthreads();
    {
        float a = d1b[tid];
        for (int k = 0; k < 256; k++) a = fmaf(x[k], d1w[k * 128 + tid], a);
        y1[tid] = fmaxf(a, 0.f);
    }
    __syncthreads();
    if (tid < 64) {
        float a = d3b[tid];
        for (int k = 0; k < 128; k++) a = fmaf(y1[k], d3w[k * 64 + tid], a);
        y2[tid] = fmaxf(a, 0.f);
    }
    __syncthreads();
    if (tid < 32) {
        float a = d5b[tid];
        for (int k = 0; k < 64; k++) a = fmaf(y2[k], d5w[k * 32 + tid], a);
        y3[tid] = fmaxf(a, 0.f);
    }
    __syncthreads();
    if (tid == 0) {
        float a = d7b[0];
        for (int k = 0; k < 32; k++) a = fmaf(y3[k], d7w[k], a);
        out[b] = 1.f / (1.f + __expf(-a));
    }
}

extern "C" void kernel_launch(void* const* d_in, const int* in_sizes, int n_in,
                              void* d_out, int out_size, void* d_ws, size_t ws_size,
                              hipStream_t stream) {
    const float* hidden  = (const float*)d_in[0];
    const int*   mask    = (const int*)d_in[1];
    const float* lstm_in = (const float*)d_in[2];
    const float* l1f_k = (const float*)d_in[4];
    const float* l1f_r = (const float*)d_in[5];
    const float* l1f_b = (const float*)d_in[6];
    const float* l1b_k = (const float*)d_in[7];
    const float* l1b_r = (const float*)d_in[8];
    const float* l1b_b = (const float*)d_in[9];
    const float* l2f_k = (const float*)d_in[10];
    const float* l2f_r = (const float*)d_in[11];
    const float* l2f_b = (const float*)d_in[12];
    const float* l2b_k = (const float*)d_in[13];
    const float* l2b_r = (const float*)d_in[14];
    const float* l2b_b = (const float*)d_in[15];
    const float* d1w = (const float*)d_in[16];
    const float* d1b = (const float*)d_in[17];
    const float* d3w = (const float*)d_in[18];
    const float* d3b = (const float*)d_in[19];
    const float* d5w = (const float*)d_in[20];
    const float* d5b = (const float*)d_in[21];
    const float* d7w = (const float*)d_in[22];
    const float* d7b = (const float*)d_in[23];

    char* p = (char*)d_ws;
    short* concatB = (short*)p; p += (size_t)3200 * 832 * 2;
    short* wk1T    = (short*)p; p += (size_t)2048 * 832 * 2;
    short* wk2T    = (short*)p; p += (size_t)1024 * 512 * 2;
    float* xz1     = (float*)p; p += (size_t)3200 * 2048 * 4;
    short* out1    = (short*)p; p += (size_t)3200 * 512 * 2;
    float* xz2     = (float*)p; p += (size_t)3200 * 1024 * 4;
    float* out2    = (float*)p; p += (size_t)64 * 256 * 4;
    unsigned int* wp1 = (unsigned int*)p; p += (size_t)2 * 32 * 1024 * 4 * 4;
    unsigned int* wp2 = (unsigned int*)p; p += (size_t)2 * 16 * 512 * 4 * 4;
    short* onehot  = (short*)p; p += (size_t)64 * 64 * 512 * 2;

    const int lds1 = R1_LDS * 1024 * 16 + 512 + 4096;  // 119296
    hipFuncSetAttribute((const void*)lstm_rec1,
                        hipFuncAttributeMaxDynamicSharedMemorySize, lds1);

    onehot_build<<<64, 256, 0, stream>>>(mask, onehot);
    prep_seg<<<1696, 256, 0, stream>>>(l1f_k, l1b_k, wk1T, l2f_k, l2b_k, wk2T,
                                       l1f_r, l1b_r, wp1, l2f_r, l2b_r, wp2,
                                       lstm_in, hidden, onehot, concatB);
    gemm_bf16<<<dim3(25, 16), 256, 0, stream>>>(concatB, wk1T, l1f_b, l1b_b, 1024,
                                                xz1, 3200, 2048, 832);
    lstm_rec1<<<128, 512, lds1, stream>>>(xz1, wp1, out1);
    gemm_bf16<<<dim3(25, 8), 256, 0, stream>>>(out1, wk2T, l2f_b, l2b_b, 512,
                                               xz2, 3200, 1024, 512);
    lstm_rec2<<<128, 512, 0, stream>>>(xz2, wp2, out2);
    dense_head<<<64, 128, 0, stream>>>(out2, d1w, d1b, d3w, d3b, d5w, d5b,
                                       d7w, d7b, (float*)d_out);
}

// Round 20
// 222.586 us; speedup vs baseline: 1.1269x; 1.1269x over previous
//
#include <hip/hip_runtime.h>
#include <hip/hip_bf16.h>

typedef __attribute__((ext_vector_type(8))) short bf16x8;
typedef __attribute__((ext_vector_type(4))) float f32x4;
typedef __attribute__((ext_vector_type(4))) unsigned int u32x4;
typedef _Float16 half2_ __attribute__((ext_vector_type(2)));

__device__ __forceinline__ unsigned short f2bf(float f) {
    unsigned int x = __float_as_uint(f);
    x += 0x7fffu + ((x >> 16) & 1u);
    return (unsigned short)(x >> 16);
}

__device__ __forceinline__ float sigmoidf_(float x) {
    return 1.f / (1.f + __expf(-x));
}
__device__ __forceinline__ float tanhf_(float x) {
    float e = __expf(-2.f * fabsf(x));
    float t = (1.f - e) / (1.f + e);
    return copysignf(t, x);
}

__device__ __forceinline__ float fdot2_(unsigned int w, unsigned int h, float acc) {
#if __has_builtin(__builtin_amdgcn_fdot2)
    return __builtin_amdgcn_fdot2(__builtin_bit_cast(half2_, w),
                                  __builtin_bit_cast(half2_, h), acc, false);
#else
    half2_ a = __builtin_bit_cast(half2_, w);
    half2_ b = __builtin_bit_cast(half2_, h);
    return acc + (float)a.x * (float)b.x + (float)a.y * (float)b.y;
#endif
}

// ---------------------------------------------------------------------------
// Prep bodies (merged into one kernel below to save launch gaps).
// ---------------------------------------------------------------------------
__device__ void convT_body(const float* __restrict__ srcF,
                           const float* __restrict__ srcB,
                           short* __restrict__ dst, int Ksrc, int Kpad,
                           int Nhalf, int bx, int by, float* tile /*64x65*/) {
    int k0 = bx * 64, n0 = by * 64;
    const float* src = (n0 < Nhalf) ? srcF : srcB;
    int ncol0 = (n0 < Nhalf) ? n0 : n0 - Nhalf;
    int c = threadIdx.x & 63;
    int r4 = threadIdx.x >> 6;
    for (int rr = r4; rr < 64; rr += 4) {
        int k = k0 + rr;
        tile[rr * 65 + c] = (k < Ksrc) ? src[(size_t)k * Nhalf + ncol0 + c] : 0.f;
    }
    __syncthreads();
    int rn = threadIdx.x >> 2, q = threadIdx.x & 3;
    short* d = dst + (size_t)(n0 + rn) * Kpad + k0 + q * 16;
    #pragma unroll
    for (int i = 0; i < 16; i++) d[i] = (short)f2bf(tile[(q * 16 + i) * 65 + rn]);
}

__device__ void conv_rec_pack_body(const float* __restrict__ WrF,
                                   const float* __restrict__ WrB,
                                   unsigned int* __restrict__ dst, int K, int N,
                                   int kq, int dir) {
    const float* src = dir ? WrB : WrF;
    int kqq = kq >> 2, q = kq & 3;
    for (int c = threadIdx.x; c < N; c += 256) {
        half2_ h;
        h.x = (_Float16)src[(size_t)(2 * kq) * N + c];
        h.y = (_Float16)src[(size_t)(2 * kq + 1) * N + c];
        dst[(((size_t)dir * (K / 8) + kqq) * N + c) * 4 + q] =
            __builtin_bit_cast(unsigned int, h);
    }
}

__device__ void onehot_body(const int* __restrict__ mask,
                            const float* __restrict__ lstm_in,
                            short* __restrict__ onehot,
                            short* __restrict__ concatB, int b) {
    int tid = threadIdx.x;
    short* oh = onehot + (size_t)b * 64 * 512;
    for (int i = tid; i < 64 * 512 / 8; i += 256) {
        bf16x8 z = {};
        *(bf16x8*)(oh + i * 8) = z;
    }
    __syncthreads();
    for (int t = tid; t < 512; t += 256) {
        unsigned int m = (unsigned int)mask[b * 512 + t];
        if (m < 50u) oh[(size_t)m * 512 + t] = (short)0x3F80;  // bf16 1.0
    }
    for (int idx = tid; idx < 50 * 64; idx += 256) {
        int m = idx >> 6, q = idx & 63;
        float v = (q < 8) ? lstm_in[(b * 50 + m) * 8 + q] : 0.f;
        concatB[(size_t)(b * 50 + m) * 832 + 768 + q] = (short)f2bf(v);
    }
}

// One kernel, ranged dispatch: 416 convT(wk1) + 128 convT(wk2) +
// 256 pack(wp1) + 128 pack(wp2) + 64 onehot = 992 blocks.
__global__ __launch_bounds__(256) void prep_all(
    const float* __restrict__ l1f_k, const float* __restrict__ l1b_k,
    short* __restrict__ wk1T,
    const float* __restrict__ l2f_k, const float* __restrict__ l2b_k,
    short* __restrict__ wk2T,
    const float* __restrict__ l1f_r, const float* __restrict__ l1b_r,
    unsigned int* __restrict__ wp1,
    const float* __restrict__ l2f_r, const float* __restrict__ l2b_r,
    unsigned int* __restrict__ wp2,
    const int* __restrict__ mask, const float* __restrict__ lstm_in,
    short* __restrict__ onehot, short* __restrict__ concatB) {
    __shared__ float tile[64 * 65];
    int blk = blockIdx.x;
    if (blk < 416) {
        convT_body(l1f_k, l1b_k, wk1T, 776, 832, 1024, blk % 13, blk / 13, tile);
    } else if (blk < 544) {
        int q = blk - 416;
        convT_body(l2f_k, l2b_k, wk2T, 512, 512, 512, q % 8, q / 8, tile);
    } else if (blk < 800) {
        int q = blk - 544;
        conv_rec_pack_body(l1f_r, l1b_r, wp1, 256, 1024, q & 127, q >> 7);
    } else if (blk < 928) {
        int q = blk - 800;
        conv_rec_pack_body(l2f_r, l2b_r, wp2, 128, 512, q & 63, q >> 6);
    } else {
        onehot_body(mask, lstm_in, onehot, concatB, blk - 928);
    }
}

// ---------------------------------------------------------------------------
// Segment-reduce as MFMA GEMM: merged[b] = onehot[b] @ hidden[b] / 50.
// ---------------------------------------------------------------------------
__global__ __launch_bounds__(256) void seg_gemm(
    const float* __restrict__ hidden, const short* __restrict__ onehot,
    short* __restrict__ concatB) {
    int b = blockIdx.x, n0 = blockIdx.y * 64;
    __shared__ short Al[64][36];
    __shared__ short Bl[64][36];
    int tid = threadIdx.x;
    int lane = tid & 63, w = tid >> 6;
    int fr = lane & 15, fq = lane >> 4;
    int wc = w * 16;
    int arow = tid >> 2, apart = tid & 3;
    int nloc = tid & 63, kq = tid >> 6;

    f32x4 acc[4] = {};

    const short* ohb = onehot + (size_t)b * 64 * 512;
    const float* hbase = hidden + (size_t)b * 512 * 768 + n0 + nloc;

    bf16x8 aReg = *(const bf16x8*)(ohb + (size_t)arow * 512 + apart * 8);
    float bReg[8];
    #pragma unroll
    for (int kk = 0; kk < 8; kk++)
        bReg[kk] = hbase[(size_t)(kq * 8 + kk) * 768];

    for (int k0 = 0; k0 < 512; k0 += 32) {
        *(bf16x8*)&Al[arow][apart * 8] = aReg;
        #pragma unroll
        for (int kk = 0; kk < 8; kk += 2) {
            unsigned int pk = (unsigned int)f2bf(bReg[kk]) |
                              ((unsigned int)f2bf(bReg[kk + 1]) << 16);
            *(unsigned int*)&Bl[nloc][kq * 8 + kk] = pk;
        }
        __syncthreads();
        if (k0 + 32 < 512) {
            int kn = k0 + 32;
            aReg = *(const bf16x8*)(ohb + (size_t)arow * 512 + kn + apart * 8);
            #pragma unroll
            for (int kk = 0; kk < 8; kk++)
                bReg[kk] = hbase[(size_t)(kn + kq * 8 + kk) * 768];
        }
        bf16x8 af[4], bfv;
        #pragma unroll
        for (int mi = 0; mi < 4; mi++)
            af[mi] = *(const bf16x8*)&Al[mi * 16 + fr][fq * 8];
        bfv = *(const bf16x8*)&Bl[wc + fr][fq * 8];
        #pragma unroll
        for (int mi = 0; mi < 4; mi++)
            acc[mi] = __builtin_amdgcn_mfma_f32_16x16x32_bf16(af[mi], bfv,
                                                              acc[mi], 0, 0, 0);
        __syncthreads();
    }
    const float inv = 1.f / 50.f;
    #pragma unroll
    for (int mi = 0; mi < 4; mi++) {
        #pragma unroll
        for (int r = 0; r < 4; r++) {
            int m = mi * 16 + fq * 4 + r;
            if (m < 50) {
                int col = n0 + wc + fr;
                concatB[(size_t)(b * 50 + m) * 832 + col] =
                    (short)f2bf(acc[mi][r] * inv);
            }
        }
    }
}

// ---------------------------------------------------------------------------
// bf16 MFMA GEMM, BK=64 (half the barriers of BK=32) + register prefetch.
// ---------------------------------------------------------------------------
__global__ __launch_bounds__(256) void gemm_bf16(
    const short* __restrict__ A, const short* __restrict__ BT,
    const float* __restrict__ biasF, const float* __restrict__ biasB, int Nhalf,
    float* __restrict__ C, int M, int N, int Kpad) {
    __shared__ short Al[128][72];
    __shared__ short Bl[128][72];
    int m0 = blockIdx.x * 128, n0 = blockIdx.y * 128;
    int tid = threadIdx.x;
    int lane = tid & 63, w = tid >> 6;
    int srow = tid >> 1, shalf = tid & 1;
    int wr = (w >> 1) * 64, wc = (w & 1) * 64;
    int fr = lane & 15, fq = lane >> 4;

    f32x4 acc[4][4] = {};

    const short* aPtr = A + (size_t)(m0 + srow) * Kpad + shalf * 32;
    const short* bPtr = BT + (size_t)(n0 + srow) * Kpad + shalf * 32;
    bf16x8 av0 = *(const bf16x8*)(aPtr);
    bf16x8 av1 = *(const bf16x8*)(aPtr + 16);
    bf16x8 bv0 = *(const bf16x8*)(bPtr);
    bf16x8 bv1 = *(const bf16x8*)(bPtr + 16);

    for (int k0 = 0; k0 < Kpad; k0 += 64) {
        *(bf16x8*)&Al[srow][shalf * 32] = av0;
        *(bf16x8*)&Al[srow][shalf * 32 + 16] = av1;
        *(bf16x8*)&Bl[srow][shalf * 32] = bv0;
        *(bf16x8*)&Bl[srow][shalf * 32 + 16] = bv1;
        __syncthreads();
        if (k0 + 64 < Kpad) {
            av0 = *(const bf16x8*)(aPtr + k0 + 64);
            av1 = *(const bf16x8*)(aPtr + k0 + 80);
            bv0 = *(const bf16x8*)(bPtr + k0 + 64);
            bv1 = *(const bf16x8*)(bPtr + k0 + 80);
        }
        #pragma unroll
        for (int ks = 0; ks < 2; ks++) {
            bf16x8 af[4], bfv[4];
            #pragma unroll
            for (int mi = 0; mi < 4; mi++)
                af[mi] = *(const bf16x8*)&Al[wr + mi * 16 + fr][ks * 32 + fq * 8];
            #pragma unroll
            for (int ni = 0; ni < 4; ni++)
                bfv[ni] = *(const bf16x8*)&Bl[wc + ni * 16 + fr][ks * 32 + fq * 8];
            #pragma unroll
            for (int mi = 0; mi < 4; mi++)
                #pragma unroll
                for (int ni = 0; ni < 4; ni++)
                    acc[mi][ni] = __builtin_amdgcn_mfma_f32_16x16x32_bf16(
                        af[mi], bfv[ni], acc[mi][ni], 0, 0, 0);
        }
        __syncthreads();
    }
    #pragma unroll
    for (int mi = 0; mi < 4; mi++)
        #pragma unroll
        for (int ni = 0; ni < 4; ni++) {
            #pragma unroll
            for (int r = 0; r < 4; r++) {
                int row = m0 + wr + mi * 16 + fq * 4 + r;
                int col = n0 + wc + ni * 16 + fr;
                float bias = (col < Nhalf) ? biasF[col] : biasB[col - Nhalf];
                C[(size_t)row * N + col] = acc[mi][ni][r] + bias;
            }
        }
}

// ---------------------------------------------------------------------------
// LSTM layer-1 recurrence (R15: 104 us). 512 threads, 2 cols each; 25
// k-groups pinned in regs/AGPRs, 7 in LDS (112 KB); 2 waves/SIMD.
// ---------------------------------------------------------------------------
#define R1_REG 25
#define R1_LDS 7

__global__ __attribute__((amdgpu_flat_work_group_size(512, 512)))
__attribute__((amdgpu_waves_per_eu(2, 2))) void lstm_rec1(
    const float* __restrict__ xz, const unsigned int* __restrict__ wp,
    short* __restrict__ out1) {
    int b = blockIdx.x >> 1, dir = blockIdx.x & 1;
    const unsigned int* wd = wp + (size_t)dir * 32 * 1024 * 4;
    extern __shared__ char smem[];
    unsigned int* Wl = (unsigned int*)smem;                            // 112 KB
    unsigned int* h2u = (unsigned int*)(smem + R1_LDS * 1024 * 16);    // 128 u32
    float* zbuf = (float*)(smem + R1_LDS * 1024 * 16 + 512);           // 1024 f32
    int tid = threadIdx.x;
    int lane = tid & 63;
    int cA = tid, cB = tid + 512;

    unsigned int wA[R1_REG * 4], wB[R1_REG * 4];
    #pragma unroll
    for (int g = 0; g < R1_REG; g++) {
        u32x4 ta = *(const u32x4*)&wd[((size_t)g * 1024 + cA) * 4];
        u32x4 tb = *(const u32x4*)&wd[((size_t)g * 1024 + cB) * 4];
        wA[g * 4 + 0] = ta.x; wA[g * 4 + 1] = ta.y;
        wA[g * 4 + 2] = ta.z; wA[g * 4 + 3] = ta.w;
        wB[g * 4 + 0] = tb.x; wB[g * 4 + 1] = tb.y;
        wB[g * 4 + 2] = tb.z; wB[g * 4 + 3] = tb.w;
    }
    // One-time pin: asm outputs are not rematerializable.
    #pragma unroll
    for (int g = 0; g < R1_REG; g++) {
        asm volatile("" : "+v"(wA[g * 4 + 0]), "+v"(wA[g * 4 + 1]),
                          "+v"(wA[g * 4 + 2]), "+v"(wA[g * 4 + 3]),
                          "+v"(wB[g * 4 + 0]), "+v"(wB[g * 4 + 1]),
                          "+v"(wB[g * 4 + 2]), "+v"(wB[g * 4 + 3]));
    }
    #pragma unroll
    for (int g = 0; g < R1_LDS; g++) {
        *(u32x4*)&Wl[(g * 1024 + cA) * 4] =
            *(const u32x4*)&wd[((size_t)(R1_REG + g) * 1024 + cA) * 4];
        *(u32x4*)&Wl[(g * 1024 + cB) * 4] =
            *(const u32x4*)&wd[((size_t)(R1_REG + g) * 1024 + cB) * 4];
    }
    if (tid < 128) h2u[tid] = 0u;
    float cstate = 0.f;
    __syncthreads();

    for (int s = 0; s < 50; s++) {
        int tt = dir ? 49 - s : s;
        const float* xrow = xz + (size_t)(b * 50 + tt) * 2048 + dir * 1024;
        float xA = xrow[cA];
        float xB = xrow[cB];
        float zA0 = 0.f, zA1 = 0.f, zA2 = 0.f, zA3 = 0.f;
        float zB0 = 0.f, zB1 = 0.f, zB2 = 0.f, zB3 = 0.f;
        unsigned int hv0 = h2u[lane];
        unsigned int hv1 = h2u[lane + 64];
        #pragma unroll
        for (int g = 0; g < R1_REG; g++) {
            unsigned int src = (g < 16) ? hv0 : hv1;
            int base = (g < 16) ? 4 * g : 4 * (g - 16);
            unsigned int h0 = __builtin_amdgcn_readlane(src, base + 0);
            unsigned int h1 = __builtin_amdgcn_readlane(src, base + 1);
            unsigned int h2 = __builtin_amdgcn_readlane(src, base + 2);
            unsigned int h3 = __builtin_amdgcn_readlane(src, base + 3);
            zA0 = fdot2_(wA[g * 4 + 0], h0, zA0);
            zA1 = fdot2_(wA[g * 4 + 1], h1, zA1);
            zA2 = fdot2_(wA[g * 4 + 2], h2, zA2);
            zA3 = fdot2_(wA[g * 4 + 3], h3, zA3);
            zB0 = fdot2_(wB[g * 4 + 0], h0, zB0);
            zB1 = fdot2_(wB[g * 4 + 1], h1, zB1);
            zB2 = fdot2_(wB[g * 4 + 2], h2, zB2);
            zB3 = fdot2_(wB[g * 4 + 3], h3, zB3);
        }
        #pragma unroll
        for (int g = 0; g < R1_LDS; g++) {
            int gg = R1_REG + g;  // 25..31, all >= 16 -> hv1
            int base = 4 * (gg - 16);
            unsigned int h0 = __builtin_amdgcn_readlane(hv1, base + 0);
            unsigned int h1 = __builtin_amdgcn_readlane(hv1, base + 1);
            unsigned int h2 = __builtin_amdgcn_readlane(hv1, base + 2);
            unsigned int h3 = __builtin_amdgcn_readlane(hv1, base + 3);
            u32x4 wa = *(const u32x4*)&Wl[(g * 1024 + cA) * 4];
            u32x4 wb = *(const u32x4*)&Wl[(g * 1024 + cB) * 4];
            zA0 = fdot2_(wa.x, h0, zA0);
            zA1 = fdot2_(wa.y, h1, zA1);
            zA2 = fdot2_(wa.z, h2, zA2);
            zA3 = fdot2_(wa.w, h3, zA3);
            zB0 = fdot2_(wb.x, h0, zB0);
            zB1 = fdot2_(wb.y, h1, zB1);
            zB2 = fdot2_(wb.z, h2, zB2);
            zB3 = fdot2_(wb.w, h3, zB3);
        }
        zbuf[cA] = (zA0 + zA1) + (zA2 + zA3) + xA;
        zbuf[cB] = (zB0 + zB1) + (zB2 + zB3) + xB;
        __syncthreads();
        if (tid < 256) {
            float iv = sigmoidf_(zbuf[tid]);
            float fv = sigmoidf_(zbuf[tid + 256]);
            float gv = tanhf_(zbuf[tid + 512]);
            float ov = sigmoidf_(zbuf[tid + 768]);
            cstate = fv * cstate + iv * gv;
            float h = ov * tanhf_(cstate);
            ((_Float16*)h2u)[tid] = (_Float16)h;
            out1[(size_t)(b * 50 + tt) * 512 + dir * 256 + tid] = (short)f2bf(h);
        }
        __syncthreads();
    }
}

// ---------------------------------------------------------------------------
// LSTM layer-2 recurrence (R10 version). 512 threads, 1 col each; 16
// k-groups pinned once; h via readlane.
// ---------------------------------------------------------------------------
__global__ __launch_bounds__(512, 2) void lstm_rec2(
    const float* __restrict__ xz, const unsigned int* __restrict__ wp,
    float* __restrict__ out2) {
    int b = blockIdx.x >> 1, dir = blockIdx.x & 1;
    const unsigned int* wd = wp + (size_t)dir * 16 * 512 * 4;
    __shared__ unsigned int h2u[64];
    __shared__ float zbuf[512];
    int tid = threadIdx.x;
    int lane = tid & 63;
    unsigned int w[64];
    #pragma unroll
    for (int g = 0; g < 16; g++) {
        u32x4 t = *(const u32x4*)&wd[((size_t)g * 512 + tid) * 4];
        w[g * 4 + 0] = t.x; w[g * 4 + 1] = t.y;
        w[g * 4 + 2] = t.z; w[g * 4 + 3] = t.w;
    }
    #pragma unroll
    for (int g = 0; g < 16; g++) {
        asm volatile("" : "+v"(w[g * 4 + 0]), "+v"(w[g * 4 + 1]),
                          "+v"(w[g * 4 + 2]), "+v"(w[g * 4 + 3]));
    }
    if (tid < 64) h2u[tid] = 0u;
    float cstate = 0.f;
    __syncthreads();

    for (int s = 0; s < 50; s++) {
        int tt = dir ? 49 - s : s;
        float xv = xz[(size_t)(b * 50 + tt) * 1024 + dir * 512 + tid];
        float z0 = 0.f, z1 = 0.f, z2 = 0.f, z3 = 0.f;
        unsigned int hv = h2u[lane];
        #pragma unroll
        for (int g = 0; g < 16; g++) {
            unsigned int h0 = __builtin_amdgcn_readlane(hv, 4 * g + 0);
            unsigned int h1 = __builtin_amdgcn_readlane(hv, 4 * g + 1);
            unsigned int h2 = __builtin_amdgcn_readlane(hv, 4 * g + 2);
            unsigned int h3 = __builtin_amdgcn_readlane(hv, 4 * g + 3);
            z0 = fdot2_(w[g * 4 + 0], h0, z0);
            z1 = fdot2_(w[g * 4 + 1], h1, z1);
            z2 = fdot2_(w[g * 4 + 2], h2, z2);
            z3 = fdot2_(w[g * 4 + 3], h3, z3);
        }
        zbuf[tid] = (z0 + z1) + (z2 + z3) + xv;
        __syncthreads();
        if (tid < 128) {
            float iv = sigmoidf_(zbuf[tid]);
            float fv = sigmoidf_(zbuf[tid + 128]);
            float gv = tanhf_(zbuf[tid + 256]);
            float ov = sigmoidf_(zbuf[tid + 384]);
            cstate = fv * cstate + iv * gv;
            float h = ov * tanhf_(cstate);
            ((_Float16*)h2u)[tid] = (_Float16)h;
            if (s == 49) out2[b * 256 + dir * 128 + tid] = h;
        }
        __syncthreads();
    }
}

// ---------------------------------------------------------------------------
// Dense head: 256->128->64->32->1 with relu/sigmoid. One block per batch.
// ---------------------------------------------------------------------------
__global__ __launch_bounds__(128) void dense_head(
    const float* __restrict__ out2,
    const float* __restrict__ d1w, const float* __restrict__ d1b,
    const float* __restrict__ d3w, const float* __restrict__ d3b,
    const float* __restrict__ d5w, const float* __restrict__ d5b,
    const float* __restrict__ d7w, const float* __restrict__ d7b,
    float* __restrict__ out) {
    int b = blockIdx.x;
    int tid = threadIdx.x;
    __shared__ float x[256], y1[128], y2[64], y3[32];
    x[tid] = out2[b * 256 + tid];
    x[tid + 128] = out2[b * 256 + tid + 128];
    __syncthreads();
    {
        float a = d1b[tid];
        for (int k = 0; k < 256; k++) a = fmaf(x[k], d1w[k * 128 + tid], a);
        y1[tid] = fmaxf(a, 0.f);
    }
    __syncthreads();
    if (tid < 64) {
        float a = d3b[tid];
        for (int k = 0; k < 128; k++) a = fmaf(y1[k], d3w[k * 64 + tid], a);
        y2[tid] = fmaxf(a, 0.f);
    }
    __syncthreads();
    if (tid < 32) {
        float a = d5b[tid];
        for (int k = 0; k < 64; k++) a = fmaf(y2[k], d5w[k * 32 + tid], a);
        y3[tid] = fmaxf(a, 0.f);
    }
    __syncthreads();
    if (tid == 0) {
        float a = d7b[0];
        for (int k = 0; k < 32; k++) a = fmaf(y3[k], d7w[k], a);
        out[b] = 1.f / (1.f + __expf(-a));
    }
}

extern "C" void kernel_launch(void* const* d_in, const int* in_sizes, int n_in,
                              void* d_out, int out_size, void* d_ws, size_t ws_size,
                              hipStream_t stream) {
    const float* hidden  = (const float*)d_in[0];
    const int*   mask    = (const int*)d_in[1];
    const float* lstm_in = (const float*)d_in[2];
    const float* l1f_k = (const float*)d_in[4];
    const float* l1f_r = (const float*)d_in[5];
    const float* l1f_b = (const float*)d_in[6];
    const float* l1b_k = (const float*)d_in[7];
    const float* l1b_r = (const float*)d_in[8];
    const float* l1b_b = (const float*)d_in[9];
    const float* l2f_k = (const float*)d_in[10];
    const float* l2f_r = (const float*)d_in[11];
    const float* l2f_b = (const float*)d_in[12];
    const float* l2b_k = (const float*)d_in[13];
    const float* l2b_r = (const float*)d_in[14];
    const float* l2b_b = (const float*)d_in[15];
    const float* d1w = (const float*)d_in[16];
    const float* d1b = (const float*)d_in[17];
    const float* d3w = (const float*)d_in[18];
    const float* d3b = (const float*)d_in[19];
    const float* d5w = (const float*)d_in[20];
    const float* d5b = (const float*)d_in[21];
    const float* d7w = (const float*)d_in[22];
    const float* d7b = (const float*)d_in[23];

    char* p = (char*)d_ws;
    short* concatB = (short*)p; p += (size_t)3200 * 832 * 2;
    short* wk1T    = (short*)p; p += (size_t)2048 * 832 * 2;
    short* wk2T    = (short*)p; p += (size_t)1024 * 512 * 2;
    float* xz1     = (float*)p; p += (size_t)3200 * 2048 * 4;
    short* out1    = (short*)p; p += (size_t)3200 * 512 * 2;
    float* xz2     = (float*)p; p += (size_t)3200 * 1024 * 4;
    float* out2    = (float*)p; p += (size_t)64 * 256 * 4;
    unsigned int* wp1 = (unsigned int*)p; p += (size_t)2 * 32 * 1024 * 4 * 4;
    unsigned int* wp2 = (unsigned int*)p; p += (size_t)2 * 16 * 512 * 4 * 4;
    short* onehot  = (short*)p; p += (size_t)64 * 64 * 512 * 2;

    const int lds1 = R1_LDS * 1024 * 16 + 512 + 4096;  // 119296
    hipFuncSetAttribute((const void*)lstm_rec1,
                        hipFuncAttributeMaxDynamicSharedMemorySize, lds1);

    prep_all<<<992, 256, 0, stream>>>(l1f_k, l1b_k, wk1T, l2f_k, l2b_k, wk2T,
                                      l1f_r, l1b_r, wp1, l2f_r, l2b_r, wp2,
                                      mask, lstm_in, onehot, concatB);
    seg_gemm<<<dim3(64, 12), 256, 0, stream>>>(hidden, onehot, concatB);
    gemm_bf16<<<dim3(25, 16), 256, 0, stream>>>(concatB, wk1T, l1f_b, l1b_b, 1024,
                                                xz1, 3200, 2048, 832);
    lstm_rec1<<<128, 512, lds1, stream>>>(xz1, wp1, out1);
    gemm_bf16<<<dim3(25, 8), 256, 0, stream>>>(out1, wk2T, l2f_b, l2b_b, 512,
                                               xz2, 3200, 1024, 512);
    lstm_rec2<<<128, 512, 0, stream>>>(xz2, wp2, out2);
    dense_head<<<64, 128, 0, stream>>>(out2, d1w, d1b, d3w, d3b, d5w, d5b,
                                       d7w, d7b, (float*)d_out);
}